// Round 1
// baseline (207.735 us; speedup 1.0000x reference)
//
#include <hip/hip_runtime.h>
#include <hip/hip_bf16.h>

// ---------------------------------------------------------------------------
// QLayer: per-type 2-layer MLP.
//   h   = relu(x_t @ W1_t + b1_t)       [16384x512]@[512x1024]   (x4 types)
//   out = h @ W2_t + b2_t, padded to 128 cols                    (x4 types)
// Strategy: convert everything to bf16 (weights pre-transposed to B^T so both
// GEMMs can use global_load_lds w16 staging), then two m97-style MFMA GEMMs.
// ---------------------------------------------------------------------------

typedef __attribute__((ext_vector_type(8))) short short8;
typedef __attribute__((ext_vector_type(4))) float f32x4;

#define NT 4
#define NNODE 16384
#define DIN 512
#define DH 1024
#define MAXO 128

static __device__ __forceinline__ ushort f2bf(float f) {
    __hip_bfloat16 h = __float2bfloat16(f);
    return *reinterpret_cast<ushort*>(&h);
}

// --- x fp32 -> bf16, [4][16384][512] flat ---------------------------------
__global__ __launch_bounds__(256) void cvt_x_kernel(
    const float* __restrict__ x0, const float* __restrict__ x1,
    const float* __restrict__ x2, const float* __restrict__ x3,
    ushort* __restrict__ out) {
    const int i = blockIdx.x * 256 + threadIdx.x;     // 8-float chunk id
    const int per_t = (NNODE * DIN) / 8;              // 2^20 chunks per type
    const int t = i >> 20;
    const int loc = i & (per_t - 1);
    const float* x = (t == 0) ? x0 : (t == 1) ? x1 : (t == 2) ? x2 : x3;
    const float4* xv = reinterpret_cast<const float4*>(x) + (size_t)loc * 2;
    float4 a = xv[0], b = xv[1];
    union { short8 v; ushort u[8]; } r;
    float f[8] = {a.x, a.y, a.z, a.w, b.x, b.y, b.z, b.w};
#pragma unroll
    for (int j = 0; j < 8; ++j) r.u[j] = f2bf(f[j]);
    reinterpret_cast<short8*>(out)[i] = r.v;
}

// --- weight transpose+convert: in fp32 [R][Cin] -> out bf16 [Cout][R] ------
// grid: (Cout/32, R/32, nT). Columns c >= Cin produce zero rows (padding).
__global__ __launch_bounds__(256) void cvt_w_t_kernel(
    const float* __restrict__ in, ushort* __restrict__ out,
    int R, int Cin, size_t in_tstride, size_t out_tstride) {
    __shared__ float tile[32][33];
    const int t = blockIdx.z;
    in += (size_t)t * in_tstride;
    out += (size_t)t * out_tstride;
    const int c0 = blockIdx.x * 32, r0 = blockIdx.y * 32;
    const int cx = threadIdx.x & 31;
    const int ry = threadIdx.x >> 5;   // 0..7
#pragma unroll
    for (int j = 0; j < 4; ++j) {
        int rr = ry + j * 8;
        int c = c0 + cx;
        tile[rr][cx] = (c < Cin) ? in[(size_t)(r0 + rr) * Cin + c] : 0.0f;
    }
    __syncthreads();
#pragma unroll
    for (int j = 0; j < 4; ++j) {
        int cc = ry + j * 8;
        out[(size_t)(c0 + cc) * R + r0 + cx] = f2bf(tile[cx][cc]);
    }
}

// --- b2 pad to [4][128] fp32 ----------------------------------------------
__global__ void pad_b2_kernel(const float* __restrict__ b0, const float* __restrict__ b1,
                              const float* __restrict__ b2, const float* __restrict__ b3,
                              float* __restrict__ out) {
    const int i = threadIdx.x;            // 0..511
    const int t = i >> 7, n = i & 127;
    const int sz[4] = {128, 96, 64, 32};
    const float* b = (t == 0) ? b0 : (t == 1) ? b1 : (t == 2) ? b2 : b3;
    out[i] = (n < sz[t]) ? b[n] : 0.0f;
}

// --- m97-style bf16 MFMA GEMM: C = A[M][K] * BT[N][K]^T + bias -------------
// 128x128 tile, BK=64, 256 threads (4 waves 2x2), wave tile 64x64,
// mfma_f32_16x16x32_bf16, global_load_lds w16 staging, linear LDS.
template <bool RELU, bool OUTBF16>
__global__ __launch_bounds__(256) void gemm_bt(
    const ushort* __restrict__ Abase, const ushort* __restrict__ Bbase,
    const float* __restrict__ biasbase, void* __restrict__ Cbase,
    int M, int N, int K,
    size_t strideA, size_t strideB, size_t strideBias, size_t strideC) {
    __shared__ ushort lsA[128 * 64];
    __shared__ ushort lsB[128 * 64];

    const int t = blockIdx.z;
    const ushort* A = Abase + (size_t)t * strideA;
    const ushort* B = Bbase + (size_t)t * strideB;
    const float* bias = biasbase + (size_t)t * strideBias;

    const int m0 = blockIdx.y * 128;
    const int n0 = blockIdx.x * 128;
    const int tid = threadIdx.x;
    const int lane = tid & 63;
    const int w = tid >> 6;
    const int wr = w >> 1, wc = w & 1;
    const int lrow = lane & 15, lgrp = lane >> 4;

    f32x4 acc[4][4] = {};

    for (int kt = 0; kt < K; kt += 64) {
        // stage A[128][64] and B(T)[128][64] tiles, linear LDS, 16B/lane
#pragma unroll
        for (int i = 0; i < 4; ++i) {
            const int s = i * 256 + tid;          // chunk id 0..1023
            const int row = s >> 3;
            const int kc = (s & 7) << 3;
            const ushort* ga = A + (size_t)(m0 + row) * K + kt + kc;
            const ushort* gb = B + (size_t)(n0 + row) * K + kt + kc;
            char* la = (char*)lsA + (size_t)(i * 256 + w * 64) * 16;
            char* lb = (char*)lsB + (size_t)(i * 256 + w * 64) * 16;
            __builtin_amdgcn_global_load_lds(
                (const __attribute__((address_space(1))) void*)ga,
                (__attribute__((address_space(3))) void*)la, 16, 0, 0);
            __builtin_amdgcn_global_load_lds(
                (const __attribute__((address_space(1))) void*)gb,
                (__attribute__((address_space(3))) void*)lb, 16, 0, 0);
        }
        __syncthreads();

#pragma unroll
        for (int kk = 0; kk < 64; kk += 32) {
            short8 af[4], bfr[4];
#pragma unroll
            for (int mi = 0; mi < 4; ++mi)
                af[mi] = *reinterpret_cast<const short8*>(
                    lsA + (wr * 64 + mi * 16 + lrow) * 64 + kk + lgrp * 8);
#pragma unroll
            for (int ni = 0; ni < 4; ++ni)
                bfr[ni] = *reinterpret_cast<const short8*>(
                    lsB + (wc * 64 + ni * 16 + lrow) * 64 + kk + lgrp * 8);
#pragma unroll
            for (int mi = 0; mi < 4; ++mi)
#pragma unroll
                for (int ni = 0; ni < 4; ++ni)
                    acc[mi][ni] = __builtin_amdgcn_mfma_f32_16x16x32_bf16(
                        af[mi], bfr[ni], acc[mi][ni], 0, 0, 0);
        }
        __syncthreads();
    }

    // epilogue: D mapping col=lane&15, row=(lane>>4)*4+reg  [measured m89/m91]
    const int crow0 = m0 + wr * 64;
    const int ccol0 = n0 + wc * 64;
#pragma unroll
    for (int ni = 0; ni < 4; ++ni) {
        const int col = ccol0 + ni * 16 + lrow;
        const float bv = bias[col];
#pragma unroll
        for (int mi = 0; mi < 4; ++mi) {
            const int row = crow0 + mi * 16 + lgrp * 4;
#pragma unroll
            for (int r = 0; r < 4; ++r) {
                float v = acc[mi][ni][r] + bv;
                if (RELU) v = fmaxf(v, 0.0f);
                if (OUTBF16) {
                    ((ushort*)Cbase)[(size_t)t * strideC + (size_t)(row + r) * N + col] =
                        f2bf(v);
                } else {
                    ((float*)Cbase)[(size_t)t * strideC + (size_t)(row + r) * N + col] = v;
                }
            }
        }
    }
}

extern "C" void kernel_launch(void* const* d_in, const int* in_sizes, int n_in,
                              void* d_out, int out_size, void* d_ws, size_t ws_size,
                              hipStream_t stream) {
    const float* x0 = (const float*)d_in[0];
    const float* x1 = (const float*)d_in[1];
    const float* x2 = (const float*)d_in[2];
    const float* x3 = (const float*)d_in[3];
    // d_in[4] = node_type (unused: nodes are blocked by type already)
    const float* W1 = (const float*)d_in[5];
    const float* b1 = (const float*)d_in[6];
    const float* W2[4] = {(const float*)d_in[7], (const float*)d_in[9],
                          (const float*)d_in[11], (const float*)d_in[13]};
    const float* b2[4] = {(const float*)d_in[8], (const float*)d_in[10],
                          (const float*)d_in[12], (const float*)d_in[14]};

    // workspace layout (bytes):
    //   H    bf16 [4][16384][1024]  134217728
    //   Xbf  bf16 [4][16384][512]    67108864
    //   W1T  bf16 [4][1024][512]      4194304
    //   W2T  bf16 [4][128][1024]      1048576
    //   b2p  f32  [4][128]                2048
    char* ws = (char*)d_ws;
    ushort* H   = (ushort*)ws;
    ushort* Xbf = (ushort*)(ws + 134217728ull);
    ushort* W1T = (ushort*)(ws + 134217728ull + 67108864ull);
    ushort* W2T = (ushort*)(ws + 134217728ull + 67108864ull + 4194304ull);
    float*  b2p = (float*)(ws + 134217728ull + 67108864ull + 4194304ull + 1048576ull);

    // conversions
    cvt_x_kernel<<<16384, 256, 0, stream>>>(x0, x1, x2, x3, Xbf);
    cvt_w_t_kernel<<<dim3(32, 16, 4), 256, 0, stream>>>(
        W1, W1T, DIN, DH, (size_t)DIN * DH, (size_t)DH * DIN);
    const int osz[4] = {128, 96, 64, 32};
    for (int t = 0; t < 4; ++t)
        cvt_w_t_kernel<<<dim3(4, 32, 1), 256, 0, stream>>>(
            W2[t], W2T + (size_t)t * MAXO * DH, DH, osz[t], 0, 0);
    pad_b2_kernel<<<1, 512, 0, stream>>>(b2[0], b2[1], b2[2], b2[3], b2p);

    // layer 1: H = relu(X @ W1 + b1), bf16 out
    gemm_bt<true, true><<<dim3(DH / 128, NNODE / 128, NT), 256, 0, stream>>>(
        Xbf, W1T, b1, H,
        NNODE, DH, DIN,
        (size_t)NNODE * DIN, (size_t)DH * DIN, (size_t)DH, (size_t)NNODE * DH);

    // layer 2: out = H @ W2 + b2 (padded cols are exactly 0), fp32 out
    gemm_bt<false, false><<<dim3(MAXO / 128, NNODE / 128, NT), 256, 0, stream>>>(
        H, W2T, b2p, d_out,
        NNODE, MAXO, DH,
        (size_t)NNODE * DH, (size_t)MAXO * DH, (size_t)MAXO, (size_t)NNODE * MAXO);
}

// Round 2
// 190.722 us; speedup vs baseline: 1.0892x; 1.0892x over previous
//
#include <hip/hip_runtime.h>
#include <hip/hip_bf16.h>

// ---------------------------------------------------------------------------
// QLayer: per-type 2-layer MLP.
//   h   = relu(x_t @ W1_t + b1_t)       [16384x512]@[512x1024]   (x4 types)
//   out = h @ W2_t + b2_t, padded to 128 cols                    (x4 types)
// Round 2: 256-tile 8-phase MFMA GEMM (T2 swizzle + T3/T4 counted vmcnt +
// T5 setprio + T1 XCD swizzle), plain HIP per the m201 template.
// ---------------------------------------------------------------------------

typedef __attribute__((ext_vector_type(8))) short short8;
typedef __attribute__((ext_vector_type(4))) float f32x4;

#define NT 4
#define NNODE 16384
#define DIN 512
#define DH 1024
#define MAXO 128

static __device__ __forceinline__ ushort f2bf(float f) {
    __hip_bfloat16 h = __float2bfloat16(f);
    return *reinterpret_cast<ushort*>(&h);
}

#define GLD(gsrc, ldst)                                                        \
    __builtin_amdgcn_global_load_lds(                                          \
        (const __attribute__((address_space(1))) void*)(gsrc),                 \
        (__attribute__((address_space(3))) void*)(ldst), 16, 0, 0)

// --- x fp32 -> bf16, [4][16384][512] flat ---------------------------------
__global__ __launch_bounds__(256) void cvt_x_kernel(
    const float* __restrict__ x0, const float* __restrict__ x1,
    const float* __restrict__ x2, const float* __restrict__ x3,
    ushort* __restrict__ out) {
    const int i = blockIdx.x * 256 + threadIdx.x;     // 8-float chunk id
    const int per_t = (NNODE * DIN) / 8;              // 2^20 chunks per type
    const int t = i >> 20;
    const int loc = i & (per_t - 1);
    const float* x = (t == 0) ? x0 : (t == 1) ? x1 : (t == 2) ? x2 : x3;
    const float4* xv = reinterpret_cast<const float4*>(x) + (size_t)loc * 2;
    float4 a = xv[0], b = xv[1];
    union { short8 v; ushort u[8]; } r;
    float f[8] = {a.x, a.y, a.z, a.w, b.x, b.y, b.z, b.w};
#pragma unroll
    for (int j = 0; j < 8; ++j) r.u[j] = f2bf(f[j]);
    reinterpret_cast<short8*>(out)[i] = r.v;
}

// --- weight transpose+convert: in fp32 [R][Cin] -> out bf16 [Cout][R] ------
__global__ __launch_bounds__(256) void cvt_w_t_kernel(
    const float* __restrict__ in, ushort* __restrict__ out,
    int R, int Cin, size_t in_tstride, size_t out_tstride) {
    __shared__ float tile[32][33];
    const int t = blockIdx.z;
    in += (size_t)t * in_tstride;
    out += (size_t)t * out_tstride;
    const int c0 = blockIdx.x * 32, r0 = blockIdx.y * 32;
    const int cx = threadIdx.x & 31;
    const int ry = threadIdx.x >> 5;   // 0..7
#pragma unroll
    for (int j = 0; j < 4; ++j) {
        int rr = ry + j * 8;
        int c = c0 + cx;
        tile[rr][cx] = (c < Cin) ? in[(size_t)(r0 + rr) * Cin + c] : 0.0f;
    }
    __syncthreads();
#pragma unroll
    for (int j = 0; j < 4; ++j) {
        int cc = ry + j * 8;
        out[(size_t)(c0 + cc) * R + r0 + cx] = f2bf(tile[cx][cc]);
    }
}

// --- b2 pad to [4][128] fp32 ----------------------------------------------
__global__ void pad_b2_kernel(const float* __restrict__ b0, const float* __restrict__ b1,
                              const float* __restrict__ b2, const float* __restrict__ b3,
                              float* __restrict__ out) {
    const int i = threadIdx.x;            // 0..511
    const int t = i >> 7, n = i & 127;
    const int sz[4] = {128, 96, 64, 32};
    const float* b = (t == 0) ? b0 : (t == 1) ? b1 : (t == 2) ? b2 : b3;
    out[i] = (n < sz[t]) ? b[n] : 0.0f;
}

// ---------------------------------------------------------------------------
// 8-phase 256-tile bf16 GEMM: C = A[M][K] * BT[N][K]^T + bias
// BM=256, BN in {256,128}, BK=64, 512 threads = 8 waves (WM=2, WN=4).
// Wave tile: 128 x (BN/4). LDS: 2 x (A 32KB + B 32or16KB), XOR-swizzled.
// Per K-tile: 4 phases; phase q: {12ish ds_read_b128; stage 1 unit (2 gload);
// barrier; MFMA x (4*NF); [vmcnt(4)@q1 / vmcnt(2)@q3]; barrier}.
// Staging unit order per tile: [B0,(B1), A-u0, A-u1] matches consumption:
//   iter start needs B*,A-u0 (quads 0,1); A-u1 (quads 2,3) needed at phase 2.
// A LDS layout: unit u holds rows {h*128+u*64+r : h=lr>>6, r=lr&63} at local
// row lr, so each 16KB unit = quads {2u,2u+1} of BOTH wave-halves.
// Swizzle (both sides): colbyte ^= (local_row & 7) << 4.
// ---------------------------------------------------------------------------
template <int BN, bool RELU, bool OUTBF16>
__global__ __launch_bounds__(512, 1) void gemm8p(
    const ushort* __restrict__ Abase, const ushort* __restrict__ Bbase,
    const float* __restrict__ biasbase, void* __restrict__ Cbase,
    int M, int N, int K, int MT,
    size_t strideA, size_t strideB, size_t strideBias, size_t strideC) {
    constexpr int NF = BN / 64;            // N-frags per wave (4 or 2)
    constexpr int NBU = BN / 128;          // B staging units (2 or 1)
    constexpr int ABYTES = 256 * 64 * 2;   // 32 KB
    constexpr int BBYTES = BN * 64 * 2;    // 32 or 16 KB
    constexpr int BUFBYTES = ABYTES + BBYTES;
    __shared__ char lds[2 * BUFBYTES];

    // XCD-bijective block swizzle (grid % 8 == 0 by construction)
    const int cpx = gridDim.x >> 3;
    const int g = blockIdx.x;
    const int wg = (g & 7) * cpx + (g >> 3);
    const int NTL = N / BN;
    const int t = wg / (MT * NTL);
    const int rmn = wg % (MT * NTL);
    const int m0 = (rmn / NTL) * 256;
    const int n0 = (rmn % NTL) * BN;

    const ushort* A = Abase + (size_t)t * strideA;
    const ushort* Bp = Bbase + (size_t)t * strideB;
    const float* bias = biasbase + (size_t)t * strideBias;

    const int tid = threadIdx.x;
    const int lane = tid & 63;
    const int w = tid >> 6;
    const int wm = w >> 2, wn = w & 3;     // WM=2, WN=4
    const int lrow = lane & 15, lgrp = lane >> 4;

    // --- precompute staging addresses (2 chunks/thread per 16KB unit) ------
    const ushort* asrc[2][2];
    const ushort* bsrc[2][2];              // [NBU<=2][2]
    int adst[2][2], bdst[2][2];
#pragma unroll
    for (int j = 0; j < 2; ++j) {
        const int cc = j * 512 + tid;          // chunk 0..1023
        const int lr = cc >> 3;                // local row 0..127
        const int cbs = ((cc & 7) * 16) ^ ((lr & 7) << 4);  // swizzled src col
#pragma unroll
        for (int u = 0; u < 2; ++u) {
            asrc[u][j] = A + (size_t)(m0 + (lr >> 6) * 128 + u * 64 + (lr & 63)) * K
                           + (cbs >> 1);
            adst[u][j] = u * 16384 + cc * 16;
        }
#pragma unroll
        for (int u = 0; u < NBU; ++u) {
            bsrc[u][j] = Bp + (size_t)(n0 + u * 128 + lr) * K + (cbs >> 1);
            bdst[u][j] = ABYTES + u * 16384 + cc * 16;
        }
    }

    f32x4 acc[8][NF] = {};

    const int NK = K / 64;

    // --- prologue: stage tile 0 into buf 0 (only place vmcnt drains to 0) --
#pragma unroll
    for (int u = 0; u < NBU; ++u) {
        GLD(bsrc[u][0], lds + bdst[u][0]);
        GLD(bsrc[u][1], lds + bdst[u][1]);
    }
#pragma unroll
    for (int u = 0; u < 2; ++u) {
        GLD(asrc[u][0], lds + adst[u][0]);
        GLD(asrc[u][1], lds + adst[u][1]);
    }
    asm volatile("s_waitcnt vmcnt(0)" ::: "memory");
    __builtin_amdgcn_s_barrier();

    for (int i = 0; i < NK; ++i) {
        const int cur = i & 1;
        const int nxtoff = (cur ^ 1) * BUFBYTES;
        const int ktn = (i + 1 < NK) ? (i + 1) * 64 : 0;  // clamp: dummy refetch
        const char* Al = lds + cur * BUFBYTES;
        const char* Bl = Al + ABYTES;
#pragma unroll
        for (int q = 0; q < 4; ++q) {
            // ds_read fragments for quad q (A: 4x b128, B: 2*NF x b128)
            short8 af[2][2], bfr[NF][2];
#pragma unroll
            for (int kkk = 0; kkk < 2; ++kkk) {
#pragma unroll
                for (int ml = 0; ml < 2; ++ml) {
                    const int lr = wm * 64 + (q & 1) * 32 + ml * 16 + lrow;
                    const int row = (q >> 1) * 128 + lr;
                    const int kb = (kkk * 64 + lgrp * 16) ^ ((lr & 7) << 4);
                    af[ml][kkk] = *(const short8*)(Al + row * 128 + kb);
                }
#pragma unroll
                for (int ni = 0; ni < NF; ++ni) {
                    const int br = wn * (NF * 16) + ni * 16 + lrow;
                    const int kb = (kkk * 64 + lgrp * 16) ^ ((br & 7) << 4);
                    bfr[ni][kkk] = *(const short8*)(Bl + br * 128 + kb);
                }
            }
            // stage unit q of tile i+1 into the other buffer
            if (q < NBU) {
                GLD(bsrc[q][0] + ktn, lds + nxtoff + bdst[q][0]);
                GLD(bsrc[q][1] + ktn, lds + nxtoff + bdst[q][1]);
            } else if (q < NBU + 2) {
                constexpr int off = 0;  // keep indices compile-time
                const int u = q - NBU;
                if (u == 0) {
                    GLD(asrc[0][0] + ktn, lds + nxtoff + adst[0][0]);
                    GLD(asrc[0][1] + ktn, lds + nxtoff + adst[0][1]);
                } else {
                    GLD(asrc[1][0] + ktn, lds + nxtoff + adst[1][0]);
                    GLD(asrc[1][1] + ktn, lds + nxtoff + adst[1][1]);
                }
                (void)off;
            }
            asm volatile("" ::: "memory");
            __builtin_amdgcn_s_barrier();          // barrier 1: phases lockstep
            __builtin_amdgcn_sched_barrier(0);
            __builtin_amdgcn_s_setprio(1);
#pragma unroll
            for (int kkk = 0; kkk < 2; ++kkk)
#pragma unroll
                for (int ml = 0; ml < 2; ++ml)
#pragma unroll
                    for (int ni = 0; ni < NF; ++ni)
                        acc[q * 2 + ml][ni] = __builtin_amdgcn_mfma_f32_16x16x32_bf16(
                            af[ml][kkk], bfr[ni][kkk], acc[q * 2 + ml][ni], 0, 0, 0);
            __builtin_amdgcn_s_setprio(0);
            // counted vmcnt (T4): protect next consumers, never drain to 0.
            //  q1: A-u1(cur tile) landed (4 newer: B0,B1|B0,Au0 of next tile)
            //  q3: B*,A-u0(next tile) landed (2 newer: A-u1 of next tile)
            if (q == 1) asm volatile("s_waitcnt vmcnt(4)" ::: "memory");
            if (q == 3) asm volatile("s_waitcnt vmcnt(2)" ::: "memory");
            asm volatile("" ::: "memory");
            __builtin_amdgcn_s_barrier();          // barrier 2
        }
    }

    // --- epilogue: C/D map col=lane&15, row=(lane>>4)*4+reg ----------------
    const int wnoff = n0 + wn * (NF * 16);
    const int wmoff = m0 + wm * 128;
#pragma unroll
    for (int ni = 0; ni < NF; ++ni) {
        const int col = wnoff + ni * 16 + lrow;
        const float bv = bias[col];
#pragma unroll
        for (int mi = 0; mi < 8; ++mi) {
            const int row = wmoff + mi * 16 + lgrp * 4;
#pragma unroll
            for (int r = 0; r < 4; ++r) {
                float v = acc[mi][ni][r] + bv;
                if (RELU) v = fmaxf(v, 0.0f);
                if (OUTBF16) {
                    ((ushort*)Cbase)[(size_t)t * strideC + (size_t)(row + r) * N + col] =
                        f2bf(v);
                } else {
                    ((float*)Cbase)[(size_t)t * strideC + (size_t)(row + r) * N + col] = v;
                }
            }
        }
    }
}

extern "C" void kernel_launch(void* const* d_in, const int* in_sizes, int n_in,
                              void* d_out, int out_size, void* d_ws, size_t ws_size,
                              hipStream_t stream) {
    const float* x0 = (const float*)d_in[0];
    const float* x1 = (const float*)d_in[1];
    const float* x2 = (const float*)d_in[2];
    const float* x3 = (const float*)d_in[3];
    // d_in[4] = node_type (unused: nodes are blocked by type already)
    const float* W1 = (const float*)d_in[5];
    const float* b1 = (const float*)d_in[6];
    const float* W2[4] = {(const float*)d_in[7], (const float*)d_in[9],
                          (const float*)d_in[11], (const float*)d_in[13]};
    const float* b2[4] = {(const float*)d_in[8], (const float*)d_in[10],
                          (const float*)d_in[12], (const float*)d_in[14]};

    // workspace layout (bytes):
    //   H    bf16 [4][16384][1024]  134217728
    //   Xbf  bf16 [4][16384][512]    67108864
    //   W1T  bf16 [4][1024][512]      4194304
    //   W2T  bf16 [4][128][1024]      1048576
    //   b2p  f32  [4][128]                2048
    char* ws = (char*)d_ws;
    ushort* H   = (ushort*)ws;
    ushort* Xbf = (ushort*)(ws + 134217728ull);
    ushort* W1T = (ushort*)(ws + 134217728ull + 67108864ull);
    ushort* W2T = (ushort*)(ws + 134217728ull + 67108864ull + 4194304ull);
    float*  b2p = (float*)(ws + 134217728ull + 67108864ull + 4194304ull + 1048576ull);

    // conversions
    cvt_x_kernel<<<16384, 256, 0, stream>>>(x0, x1, x2, x3, Xbf);
    cvt_w_t_kernel<<<dim3(32, 16, 4), 256, 0, stream>>>(
        W1, W1T, DIN, DH, (size_t)DIN * DH, (size_t)DH * DIN);
    const int osz[4] = {128, 96, 64, 32};
    for (int t = 0; t < 4; ++t)
        cvt_w_t_kernel<<<dim3(4, 32, 1), 256, 0, stream>>>(
            W2[t], W2T + (size_t)t * MAXO * DH, DH, osz[t], 0, 0);
    pad_b2_kernel<<<1, 512, 0, stream>>>(b2[0], b2[1], b2[2], b2[3], b2p);

    // layer 1: H = relu(X @ W1 + b1), bf16 out
    // grid: 64 m-tiles x 4 n-tiles x 4 types = 1024 (n fastest for A reuse)
    gemm8p<256, true, true><<<1024, 512, 0, stream>>>(
        Xbf, W1T, b1, H,
        NNODE, DH, DIN, NNODE / 256,
        (size_t)NNODE * DIN, (size_t)DH * DIN, (size_t)DH, (size_t)NNODE * DH);

    // layer 2: out = H @ W2 + b2 (padded cols exactly 0), fp32 out
    // grid: 64 m-tiles x 1 n-tile x 4 types = 256
    gemm8p<128, false, false><<<256, 512, 0, stream>>>(
        H, W2T, b2p, d_out,
        NNODE, MAXO, DH, NNODE / 256,
        (size_t)NNODE * DH, (size_t)MAXO * DH, (size_t)MAXO, (size_t)NNODE * MAXO);
}

// Round 3
// 184.634 us; speedup vs baseline: 1.1251x; 1.0330x over previous
//
#include <hip/hip_runtime.h>
#include <hip/hip_bf16.h>

// ---------------------------------------------------------------------------
// QLayer: per-type 2-layer MLP.
//   h   = relu(x_t @ W1_t + b1_t)       [16384x512]@[512x1024]   (x4 types)
//   out = h @ W2_t + b2_t, padded to 128 cols                    (x4 types)
// Round 3: 8-phase 256-tile GEMM with B-frags hoisted to registers (once per
// K-tile) and A staged in 4 quadrant-units so phase q consumes unit q —
// makes the counted-vmcnt schedule both correct and LDS-balanced.
// ---------------------------------------------------------------------------

typedef __attribute__((ext_vector_type(8))) short short8;
typedef __attribute__((ext_vector_type(4))) float f32x4;

#define NT 4
#define NNODE 16384
#define DIN 512
#define DH 1024
#define MAXO 128

static __device__ __forceinline__ ushort f2bf(float f) {
    __hip_bfloat16 h = __float2bfloat16(f);
    return *reinterpret_cast<ushort*>(&h);
}

#define GLD(gsrc, ldst)                                                        \
    __builtin_amdgcn_global_load_lds(                                          \
        (const __attribute__((address_space(1))) void*)(gsrc),                 \
        (__attribute__((address_space(3))) void*)(ldst), 16, 0, 0)

// --- x fp32 -> bf16, [4][16384][512] flat ---------------------------------
__global__ __launch_bounds__(256) void cvt_x_kernel(
    const float* __restrict__ x0, const float* __restrict__ x1,
    const float* __restrict__ x2, const float* __restrict__ x3,
    ushort* __restrict__ out) {
    const int i = blockIdx.x * 256 + threadIdx.x;     // 8-float chunk id
    const int per_t = (NNODE * DIN) / 8;              // 2^20 chunks per type
    const int t = i >> 20;
    const int loc = i & (per_t - 1);
    const float* x = (t == 0) ? x0 : (t == 1) ? x1 : (t == 2) ? x2 : x3;
    const float4* xv = reinterpret_cast<const float4*>(x) + (size_t)loc * 2;
    float4 a = xv[0], b = xv[1];
    union { short8 v; ushort u[8]; } r;
    float f[8] = {a.x, a.y, a.z, a.w, b.x, b.y, b.z, b.w};
#pragma unroll
    for (int j = 0; j < 8; ++j) r.u[j] = f2bf(f[j]);
    reinterpret_cast<short8*>(out)[i] = r.v;
}

// --- weight transpose+convert: in fp32 [R][Cin] -> out bf16 [Cout][R] ------
__global__ __launch_bounds__(256) void cvt_w_t_kernel(
    const float* __restrict__ in, ushort* __restrict__ out,
    int R, int Cin, size_t in_tstride, size_t out_tstride) {
    __shared__ float tile[32][33];
    const int t = blockIdx.z;
    in += (size_t)t * in_tstride;
    out += (size_t)t * out_tstride;
    const int c0 = blockIdx.x * 32, r0 = blockIdx.y * 32;
    const int cx = threadIdx.x & 31;
    const int ry = threadIdx.x >> 5;   // 0..7
#pragma unroll
    for (int j = 0; j < 4; ++j) {
        int rr = ry + j * 8;
        int c = c0 + cx;
        tile[rr][cx] = (c < Cin) ? in[(size_t)(r0 + rr) * Cin + c] : 0.0f;
    }
    __syncthreads();
#pragma unroll
    for (int j = 0; j < 4; ++j) {
        int cc = ry + j * 8;
        out[(size_t)(c0 + cc) * R + r0 + cx] = f2bf(tile[cx][cc]);
    }
}

// --- b2 pad to [4][128] fp32 ----------------------------------------------
__global__ void pad_b2_kernel(const float* __restrict__ b0, const float* __restrict__ b1,
                              const float* __restrict__ b2, const float* __restrict__ b3,
                              float* __restrict__ out) {
    const int i = threadIdx.x;            // 0..511
    const int t = i >> 7, n = i & 127;
    const int sz[4] = {128, 96, 64, 32};
    const float* b = (t == 0) ? b0 : (t == 1) ? b1 : (t == 2) ? b2 : b3;
    out[i] = (n < sz[t]) ? b[n] : 0.0f;
}

// ---------------------------------------------------------------------------
// 8-phase 256-tile bf16 GEMM: C = A[M][K] * BT[N][K]^T + bias
// BM=256, BN in {256,128}, BK=64, 512 threads = 8 waves (WM=2, WN=4).
// Wave tile: 128 x (BN/4). LDS: 2 x (A 32KB + B), XOR-swizzled both sides.
//
// A LDS layout: 4 units of 8KB; unit q = rows {q*32..q*32+31} u {128+q*32..}
// so phase q consumes exactly unit q (for both wm halves). B consumed at
// phase 0 only (frags hoisted to registers for the whole K-tile).
//
// Staging of tile i+1 (BN=256): q0:B0 q1:B1 q2:A01 q3:A23  (2 GLD each)
//                    (BN=128): q0:B0 q1:A01 q2:A23 q3:-
// Waits: end-q1 vmcnt(4) lands A23(cur);  end-q3 vmcnt(2) lands B+A01(next),
// leaves A23(next) in flight. Last tile: q1 drains to 0 (nothing staged).
// ---------------------------------------------------------------------------
template <int BN, bool RELU, bool OUTBF16>
__global__ __launch_bounds__(512, 1) void gemm8p(
    const ushort* __restrict__ Abase, const ushort* __restrict__ Bbase,
    const float* __restrict__ biasbase, void* __restrict__ Cbase,
    int M, int N, int K, int MT,
    size_t strideA, size_t strideB, size_t strideBias, size_t strideC) {
    constexpr int NF = BN / 64;            // N-frags per wave (4 or 2)
    constexpr int NBU = BN / 128;          // B staging units (2 or 1)
    constexpr int ABYTES = 256 * 64 * 2;   // 32 KB (4 units of 8 KB)
    constexpr int BBYTES = BN * 64 * 2;    // 32 or 16 KB
    constexpr int BUFBYTES = ABYTES + BBYTES;
    __shared__ char lds[2 * BUFBYTES];

    // XCD-bijective block swizzle (grid % 8 == 0 by construction)
    const int cpx = gridDim.x >> 3;
    const int g = blockIdx.x;
    const int wg = (g & 7) * cpx + (g >> 3);
    const int NTL = N / BN;
    const int t = wg / (MT * NTL);
    const int rmn = wg % (MT * NTL);
    const int m0 = (rmn / NTL) * 256;
    const int n0 = (rmn % NTL) * BN;

    const ushort* A = Abase + (size_t)t * strideA;
    const ushort* Bp = Bbase + (size_t)t * strideB;
    const float* bias = biasbase + (size_t)t * strideBias;

    const int tid = threadIdx.x;
    const int lane = tid & 63;
    const int w = tid >> 6;
    const int wm = w >> 2, wn = w & 3;     // WM=2, WN=4
    const int lrow = lane & 15, lgrp = lane >> 4;

    // --- staging addresses -------------------------------------------------
    // A: 1 chunk/thread per 8KB unit. local row lr = tid>>3 (0..63):
    //    lr<32 -> wm0 rows (q*32+lr), lr>=32 -> wm1 rows (128+q*32+lr-32)
    const ushort* asrc[4];
    {
        const int lr = tid >> 3, c8 = tid & 7;
        const int cbs = (c8 * 16) ^ ((lr & 7) << 4);
#pragma unroll
        for (int u = 0; u < 4; ++u)
            asrc[u] = A + (size_t)(m0 + (lr >> 5) * 128 + u * 32 + (lr & 31)) * K
                        + (cbs >> 1);
    }
    // B: 2 chunks/thread per 16KB unit (rows u*128..u*128+127)
    const ushort* bsrc[NBU][2];
    int bdst[NBU][2];
#pragma unroll
    for (int j = 0; j < 2; ++j) {
        const int cc = j * 512 + tid;          // chunk 0..1023
        const int lr = cc >> 3;                // local row 0..127
        const int cbs = ((cc & 7) * 16) ^ ((lr & 7) << 4);
#pragma unroll
        for (int u = 0; u < NBU; ++u) {
            bsrc[u][j] = Bp + (size_t)(n0 + u * 128 + lr) * K + (cbs >> 1);
            bdst[u][j] = ABYTES + u * 16384 + cc * 16;
        }
    }
    const int adst = tid * 16;                 // + q*8192 per unit

    f32x4 acc[8][NF] = {};
    const int NK = K / 64;

    // --- prologue: stage tile 0 into buf 0 ---------------------------------
#pragma unroll
    for (int u = 0; u < NBU; ++u) {
        GLD(bsrc[u][0], lds + bdst[u][0]);
        GLD(bsrc[u][1], lds + bdst[u][1]);
    }
#pragma unroll
    for (int u = 0; u < 4; ++u) GLD(asrc[u], lds + u * 8192 + adst);
    asm volatile("s_waitcnt vmcnt(0)" ::: "memory");
    __builtin_amdgcn_s_barrier();

    for (int i = 0; i < NK; ++i) {
        const int cur = i & 1;
        const int nxtoff = (cur ^ 1) * BUFBYTES;
        const int ktn = (i + 1) * 64;
        const bool st = (i + 1 < NK);
        const char* Al = lds + cur * BUFBYTES;
        const char* Bl = Al + ABYTES;
        short8 bfr[NF][2];
#pragma unroll
        for (int q = 0; q < 4; ++q) {
            // B fragments: read once per K-tile (phase 0), live all phases
            if (q == 0) {
#pragma unroll
                for (int kkk = 0; kkk < 2; ++kkk)
#pragma unroll
                    for (int ni = 0; ni < NF; ++ni) {
                        const int br = wn * (NF * 16) + ni * 16 + lrow;
                        const int kb = (kkk * 64 + lgrp * 16) ^ ((br & 7) << 4);
                        bfr[ni][kkk] = *(const short8*)(Bl + br * 128 + kb);
                    }
            }
            // A fragments for quadrant q (unit q): 4 x ds_read_b128
            short8 af[2][2];
#pragma unroll
            for (int kkk = 0; kkk < 2; ++kkk)
#pragma unroll
                for (int ml = 0; ml < 2; ++ml) {
                    const int lr = wm * 32 + ml * 16 + lrow;
                    const int kb = (kkk * 64 + lgrp * 16) ^ ((lr & 7) << 4);
                    af[ml][kkk] = *(const short8*)(Al + q * 8192 + lr * 128 + kb);
                }
            // stage one unit of tile i+1 into the other buffer
            if (st) {
                if constexpr (NBU == 2) {
                    if (q == 0) { GLD(bsrc[0][0] + ktn, lds + nxtoff + bdst[0][0]);
                                  GLD(bsrc[0][1] + ktn, lds + nxtoff + bdst[0][1]); }
                    if (q == 1) { GLD(bsrc[1][0] + ktn, lds + nxtoff + bdst[1][0]);
                                  GLD(bsrc[1][1] + ktn, lds + nxtoff + bdst[1][1]); }
                    if (q == 2) { GLD(asrc[0] + ktn, lds + nxtoff + adst);
                                  GLD(asrc[1] + ktn, lds + nxtoff + 8192 + adst); }
                    if (q == 3) { GLD(asrc[2] + ktn, lds + nxtoff + 16384 + adst);
                                  GLD(asrc[3] + ktn, lds + nxtoff + 24576 + adst); }
                } else {
                    if (q == 0) { GLD(bsrc[0][0] + ktn, lds + nxtoff + bdst[0][0]);
                                  GLD(bsrc[0][1] + ktn, lds + nxtoff + bdst[0][1]); }
                    if (q == 1) { GLD(asrc[0] + ktn, lds + nxtoff + adst);
                                  GLD(asrc[1] + ktn, lds + nxtoff + 8192 + adst); }
                    if (q == 2) { GLD(asrc[2] + ktn, lds + nxtoff + 16384 + adst);
                                  GLD(asrc[3] + ktn, lds + nxtoff + 24576 + adst); }
                }
            }
            asm volatile("" ::: "memory");
            __builtin_amdgcn_s_barrier();          // barrier 1
            __builtin_amdgcn_sched_barrier(0);
            __builtin_amdgcn_s_setprio(1);
#pragma unroll
            for (int kkk = 0; kkk < 2; ++kkk)
#pragma unroll
                for (int ml = 0; ml < 2; ++ml)
#pragma unroll
                    for (int ni = 0; ni < NF; ++ni)
                        acc[q * 2 + ml][ni] = __builtin_amdgcn_mfma_f32_16x16x32_bf16(
                            af[ml][kkk], bfr[ni][kkk], acc[q * 2 + ml][ni], 0, 0, 0);
            __builtin_amdgcn_s_setprio(0);
            // counted waits (T4): never 0 mid-loop
            if (q == 1) {
                if (st) asm volatile("s_waitcnt vmcnt(4)" ::: "memory");
                else    asm volatile("s_waitcnt vmcnt(0)" ::: "memory");
            }
            if (q == 3 && st) asm volatile("s_waitcnt vmcnt(2)" ::: "memory");
            asm volatile("" ::: "memory");
            __builtin_amdgcn_s_barrier();          // barrier 2
        }
    }

    // --- epilogue: C/D map col=lane&15, row=(lane>>4)*4+reg ----------------
    const int wnoff = n0 + wn * (NF * 16);
    const int wmoff = m0 + wm * 128;
#pragma unroll
    for (int ni = 0; ni < NF; ++ni) {
        const int col = wnoff + ni * 16 + lrow;
        const float bv = bias[col];
#pragma unroll
        for (int mi = 0; mi < 8; ++mi) {
            const int row = wmoff + mi * 16 + lgrp * 4;
#pragma unroll
            for (int r = 0; r < 4; ++r) {
                float v = acc[mi][ni][r] + bv;
                if (RELU) v = fmaxf(v, 0.0f);
                if (OUTBF16) {
                    ((ushort*)Cbase)[(size_t)t * strideC + (size_t)(row + r) * N + col] =
                        f2bf(v);
                } else {
                    ((float*)Cbase)[(size_t)t * strideC + (size_t)(row + r) * N + col] = v;
                }
            }
        }
    }
}

extern "C" void kernel_launch(void* const* d_in, const int* in_sizes, int n_in,
                              void* d_out, int out_size, void* d_ws, size_t ws_size,
                              hipStream_t stream) {
    const float* x0 = (const float*)d_in[0];
    const float* x1 = (const float*)d_in[1];
    const float* x2 = (const float*)d_in[2];
    const float* x3 = (const float*)d_in[3];
    // d_in[4] = node_type (unused: nodes are blocked by type already)
    const float* W1 = (const float*)d_in[5];
    const float* b1 = (const float*)d_in[6];
    const float* W2[4] = {(const float*)d_in[7], (const float*)d_in[9],
                          (const float*)d_in[11], (const float*)d_in[13]};
    const float* b2[4] = {(const float*)d_in[8], (const float*)d_in[10],
                          (const float*)d_in[12], (const float*)d_in[14]};

    // workspace layout (bytes):
    //   H    bf16 [4][16384][1024]  134217728
    //   Xbf  bf16 [4][16384][512]    67108864
    //   W1T  bf16 [4][1024][512]      4194304
    //   W2T  bf16 [4][128][1024]      1048576
    //   b2p  f32  [4][128]                2048
    char* ws = (char*)d_ws;
    ushort* H   = (ushort*)ws;
    ushort* Xbf = (ushort*)(ws + 134217728ull);
    ushort* W1T = (ushort*)(ws + 134217728ull + 67108864ull);
    ushort* W2T = (ushort*)(ws + 134217728ull + 67108864ull + 4194304ull);
    float*  b2p = (float*)(ws + 134217728ull + 67108864ull + 4194304ull + 1048576ull);

    // conversions
    cvt_x_kernel<<<16384, 256, 0, stream>>>(x0, x1, x2, x3, Xbf);
    cvt_w_t_kernel<<<dim3(32, 16, 4), 256, 0, stream>>>(
        W1, W1T, DIN, DH, (size_t)DIN * DH, (size_t)DH * DIN);
    const int osz[4] = {128, 96, 64, 32};
    for (int t = 0; t < 4; ++t)
        cvt_w_t_kernel<<<dim3(4, 32, 1), 256, 0, stream>>>(
            W2[t], W2T + (size_t)t * MAXO * DH, DH, osz[t], 0, 0);
    pad_b2_kernel<<<1, 512, 0, stream>>>(b2[0], b2[1], b2[2], b2[3], b2p);

    // layer 1: H = relu(X @ W1 + b1), bf16 out
    // grid: 64 m-tiles x 4 n-tiles x 4 types = 1024 (n fastest for A reuse)
    gemm8p<256, true, true><<<1024, 512, 0, stream>>>(
        Xbf, W1T, b1, H,
        NNODE, DH, DIN, NNODE / 256,
        (size_t)NNODE * DIN, (size_t)DH * DIN, (size_t)DH, (size_t)NNODE * DH);

    // layer 2: out = H @ W2 + b2 (padded cols exactly 0), fp32 out
    // grid: 64 m-tiles x 1 n-tile x 4 types = 256
    gemm8p<128, false, false><<<256, 512, 0, stream>>>(
        H, W2T, b2p, d_out,
        NNODE, MAXO, DH, NNODE / 256,
        (size_t)NNODE * DH, (size_t)MAXO * DH, (size_t)MAXO, (size_t)NNODE * MAXO);
}

// Round 4
// 179.327 us; speedup vs baseline: 1.1584x; 1.0296x over previous
//
#include <hip/hip_runtime.h>
#include <hip/hip_bf16.h>

// ---------------------------------------------------------------------------
// QLayer: per-type 2-layer MLP.
//   h   = relu(x_t @ W1_t + b1_t)       [16384x512]@[512x1024]   (x4 types)
//   out = h @ W2_t + b2_t, padded to 128 cols                    (x4 types)
// Round 4: 2-phase K-tile schedule (amortize barrier/wait overhead: 32 MFMA
// per phase), swapped-operand MFMA for a vectorized (8B/16B) epilogue.
// ---------------------------------------------------------------------------

typedef __attribute__((ext_vector_type(8))) short short8;
typedef __attribute__((ext_vector_type(4))) float f32x4;

#define NT 4
#define NNODE 16384
#define DIN 512
#define DH 1024
#define MAXO 128

static __device__ __forceinline__ ushort f2bf(float f) {
    __hip_bfloat16 h = __float2bfloat16(f);
    return *reinterpret_cast<ushort*>(&h);
}

#define GLD(gsrc, ldst)                                                        \
    __builtin_amdgcn_global_load_lds(                                          \
        (const __attribute__((address_space(1))) void*)(gsrc),                 \
        (__attribute__((address_space(3))) void*)(ldst), 16, 0, 0)

// --- x fp32 -> bf16, [4][16384][512] flat ---------------------------------
__global__ __launch_bounds__(256) void cvt_x_kernel(
    const float* __restrict__ x0, const float* __restrict__ x1,
    const float* __restrict__ x2, const float* __restrict__ x3,
    ushort* __restrict__ out) {
    const int i = blockIdx.x * 256 + threadIdx.x;     // 8-float chunk id
    const int per_t = (NNODE * DIN) / 8;              // 2^20 chunks per type
    const int t = i >> 20;
    const int loc = i & (per_t - 1);
    const float* x = (t == 0) ? x0 : (t == 1) ? x1 : (t == 2) ? x2 : x3;
    const float4* xv = reinterpret_cast<const float4*>(x) + (size_t)loc * 2;
    float4 a = xv[0], b = xv[1];
    union { short8 v; ushort u[8]; } r;
    float f[8] = {a.x, a.y, a.z, a.w, b.x, b.y, b.z, b.w};
#pragma unroll
    for (int j = 0; j < 8; ++j) r.u[j] = f2bf(f[j]);
    reinterpret_cast<short8*>(out)[i] = r.v;
}

// --- weight transpose+convert: in fp32 [R][Cin] -> out bf16 [Cout][R] ------
__global__ __launch_bounds__(256) void cvt_w_t_kernel(
    const float* __restrict__ in, ushort* __restrict__ out,
    int R, int Cin, size_t in_tstride, size_t out_tstride) {
    __shared__ float tile[32][33];
    const int t = blockIdx.z;
    in += (size_t)t * in_tstride;
    out += (size_t)t * out_tstride;
    const int c0 = blockIdx.x * 32, r0 = blockIdx.y * 32;
    const int cx = threadIdx.x & 31;
    const int ry = threadIdx.x >> 5;   // 0..7
#pragma unroll
    for (int j = 0; j < 4; ++j) {
        int rr = ry + j * 8;
        int c = c0 + cx;
        tile[rr][cx] = (c < Cin) ? in[(size_t)(r0 + rr) * Cin + c] : 0.0f;
    }
    __syncthreads();
#pragma unroll
    for (int j = 0; j < 4; ++j) {
        int cc = ry + j * 8;
        out[(size_t)(c0 + cc) * R + r0 + cx] = f2bf(tile[cx][cc]);
    }
}

// --- b2 pad to [4][128] fp32 ----------------------------------------------
__global__ void pad_b2_kernel(const float* __restrict__ b0, const float* __restrict__ b1,
                              const float* __restrict__ b2, const float* __restrict__ b3,
                              float* __restrict__ out) {
    const int i = threadIdx.x;            // 0..511
    const int t = i >> 7, n = i & 127;
    const int sz[4] = {128, 96, 64, 32};
    const float* b = (t == 0) ? b0 : (t == 1) ? b1 : (t == 2) ? b2 : b3;
    out[i] = (n < sz[t]) ? b[n] : 0.0f;
}

// ---------------------------------------------------------------------------
// 2-phase 256-tile bf16 GEMM: C = A[M][K] * BT[N][K]^T + bias
// BM=256, BN in {256,128}, BK=64, 512 threads = 8 waves (WM=2, WN=4).
// Wave tile 128 x (BN/4). LDS: dbuf x (A 32KB [2 units] + B), XOR-swizzled.
//
// A LDS: 2 units of 16KB; unit h = rows {h*64..h*64+63} u {128+h*64..+63}
// (local lr 0..127: row = (lr>>6)*128 + h*64 + (lr&63)). Phase h consumes
// unit h. All B-frags read at phase 0 (held in regs for the tile).
//
// Per K-tile: phase0 {read B(8/4)+A-u0(8); stage B(next); bar; 32 MFMA;
// vmcnt(4|2); bar}  phase1 {read A-u1(8); stage A0,A1(next); bar; 32 MFMA;
// vmcnt(2); bar}.  Waits retire exactly the next phase's inputs; never 0
// mid-loop. MFMA operands swapped: D-row dim = n -> lane holds 4 consecutive
// n values (reg r) => 8B/16B vectorized C-stores.
// ---------------------------------------------------------------------------
template <int BN, bool RELU, bool OUTBF16>
__global__ __launch_bounds__(512, 1) void gemm2p(
    const ushort* __restrict__ Abase, const ushort* __restrict__ Bbase,
    const float* __restrict__ biasbase, void* __restrict__ Cbase,
    int M, int N, int K, int MT,
    size_t strideA, size_t strideB, size_t strideBias, size_t strideC) {
    constexpr int NF = BN / 64;            // N-frags per wave (4 or 2)
    constexpr int NBU = BN / 128;          // B staging units (2 or 1)
    constexpr int ABYTES = 256 * 64 * 2;   // 32 KB (2 units of 16 KB)
    constexpr int BBYTES = BN * 64 * 2;    // 32 or 16 KB
    constexpr int BUFBYTES = ABYTES + BBYTES;
    __shared__ char lds[2 * BUFBYTES];

    // XCD-bijective block swizzle (grid % 8 == 0 by construction)
    const int cpx = gridDim.x >> 3;
    const int g = blockIdx.x;
    const int wg = (g & 7) * cpx + (g >> 3);
    const int NTL = N / BN;
    const int t = wg / (MT * NTL);
    const int rmn = wg % (MT * NTL);
    const int m0 = (rmn / NTL) * 256;
    const int n0 = (rmn % NTL) * BN;

    const ushort* A = Abase + (size_t)t * strideA;
    const ushort* Bp = Bbase + (size_t)t * strideB;
    const float* bias = biasbase + (size_t)t * strideBias;

    const int tid = threadIdx.x;
    const int lane = tid & 63;
    const int w = tid >> 6;
    const int wm = w >> 2, wn = w & 3;     // WM=2, WN=4
    const int lrow = lane & 15, lgrp = lane >> 4;

    // --- staging addresses: 2 chunks/thread per 16KB unit ------------------
    const ushort* asrc[2][2];
    const ushort* bsrc[NBU][2];
    int adst[2][2], bdst[NBU][2];
#pragma unroll
    for (int j = 0; j < 2; ++j) {
        const int cc = j * 512 + tid;          // chunk 0..1023
        const int lr = cc >> 3;                // local row 0..127
        const int cbs = ((cc & 7) * 16) ^ ((lr & 7) << 4);  // swizzled src col
#pragma unroll
        for (int u = 0; u < 2; ++u) {
            asrc[u][j] = A + (size_t)(m0 + (lr >> 6) * 128 + u * 64 + (lr & 63)) * K
                           + (cbs >> 1);
            adst[u][j] = u * 16384 + cc * 16;
        }
#pragma unroll
        for (int u = 0; u < NBU; ++u) {
            bsrc[u][j] = Bp + (size_t)(n0 + u * 128 + lr) * K + (cbs >> 1);
            bdst[u][j] = ABYTES + u * 16384 + cc * 16;
        }
    }

    f32x4 acc[8][NF] = {};
    const int NK = K / 64;

    // --- prologue: stage tile 0 into buf 0 ---------------------------------
#pragma unroll
    for (int u = 0; u < NBU; ++u) {
        GLD(bsrc[u][0], lds + bdst[u][0]);
        GLD(bsrc[u][1], lds + bdst[u][1]);
    }
#pragma unroll
    for (int u = 0; u < 2; ++u) {
        GLD(asrc[u][0], lds + adst[u][0]);
        GLD(asrc[u][1], lds + adst[u][1]);
    }
    asm volatile("s_waitcnt vmcnt(0)" ::: "memory");
    __builtin_amdgcn_s_barrier();

    for (int i = 0; i < NK; ++i) {
        const int cur = i & 1;
        const int nxtoff = (cur ^ 1) * BUFBYTES;
        const int ktn = (i + 1) * 64;
        const bool st = (i + 1 < NK);
        const char* Al = lds + cur * BUFBYTES;
        const char* Bl = Al + ABYTES;
        short8 bfr[NF][2];

        // ================= phase 0 (consumes B + A-unit0) ==================
        {
#pragma unroll
            for (int kkk = 0; kkk < 2; ++kkk)
#pragma unroll
                for (int ni = 0; ni < NF; ++ni) {
                    const int br = wn * (NF * 16) + ni * 16 + lrow;
                    const int kb = (kkk * 64 + lgrp * 16) ^ ((br & 7) << 4);
                    bfr[ni][kkk] = *(const short8*)(Bl + br * 128 + kb);
                }
            short8 af[4][2];
#pragma unroll
            for (int kkk = 0; kkk < 2; ++kkk)
#pragma unroll
                for (int ml = 0; ml < 4; ++ml) {
                    const int lr = wm * 64 + ml * 16 + lrow;
                    const int kb = (kkk * 64 + lgrp * 16) ^ ((lr & 7) << 4);
                    af[ml][kkk] = *(const short8*)(Al + lr * 128 + kb);
                }
            if (st) {
#pragma unroll
                for (int u = 0; u < NBU; ++u) {
                    GLD(bsrc[u][0] + ktn, lds + nxtoff + bdst[u][0]);
                    GLD(bsrc[u][1] + ktn, lds + nxtoff + bdst[u][1]);
                }
            }
            asm volatile("" ::: "memory");
            __builtin_amdgcn_s_barrier();
            __builtin_amdgcn_sched_barrier(0);
            __builtin_amdgcn_s_setprio(1);
#pragma unroll
            for (int kkk = 0; kkk < 2; ++kkk)
#pragma unroll
                for (int ml = 0; ml < 4; ++ml)
#pragma unroll
                    for (int ni = 0; ni < NF; ++ni)
                        acc[ml][ni] = __builtin_amdgcn_mfma_f32_16x16x32_bf16(
                            bfr[ni][kkk], af[ml][kkk], acc[ml][ni], 0, 0, 0);
            __builtin_amdgcn_s_setprio(0);
            // retire A-unit1(cur); newest allowed = B(next) just issued
            if (st) {
                if constexpr (NBU == 2)
                    asm volatile("s_waitcnt vmcnt(4)" ::: "memory");
                else
                    asm volatile("s_waitcnt vmcnt(2)" ::: "memory");
            } else {
                asm volatile("s_waitcnt vmcnt(0)" ::: "memory");
            }
            asm volatile("" ::: "memory");
            __builtin_amdgcn_s_barrier();
        }

        // ================= phase 1 (consumes A-unit1) ======================
        {
            short8 af[4][2];
#pragma unroll
            for (int kkk = 0; kkk < 2; ++kkk)
#pragma unroll
                for (int ml = 0; ml < 4; ++ml) {
                    const int lr = wm * 64 + ml * 16 + lrow;
                    const int kb = (kkk * 64 + lgrp * 16) ^ ((lr & 7) << 4);
                    af[ml][kkk] = *(const short8*)(Al + 16384 + lr * 128 + kb);
                }
            if (st) {
                GLD(asrc[0][0] + ktn, lds + nxtoff + adst[0][0]);
                GLD(asrc[0][1] + ktn, lds + nxtoff + adst[0][1]);
                GLD(asrc[1][0] + ktn, lds + nxtoff + adst[1][0]);
                GLD(asrc[1][1] + ktn, lds + nxtoff + adst[1][1]);
            }
            asm volatile("" ::: "memory");
            __builtin_amdgcn_s_barrier();
            __builtin_amdgcn_sched_barrier(0);
            __builtin_amdgcn_s_setprio(1);
#pragma unroll
            for (int kkk = 0; kkk < 2; ++kkk)
#pragma unroll
                for (int ml = 0; ml < 4; ++ml)
#pragma unroll
                    for (int ni = 0; ni < NF; ++ni)
                        acc[4 + ml][ni] = __builtin_amdgcn_mfma_f32_16x16x32_bf16(
                            bfr[ni][kkk], af[ml][kkk], acc[4 + ml][ni], 0, 0, 0);
            __builtin_amdgcn_s_setprio(0);
            // retire B(next)+A-unit0(next); newest allowed = A-unit1(next)
            if (st) asm volatile("s_waitcnt vmcnt(2)" ::: "memory");
            asm volatile("" ::: "memory");
            __builtin_amdgcn_s_barrier();
        }
    }

    // --- epilogue (swapped operands): lane holds 4 consecutive n at reg r --
    // m = wmoff + mi*16 + lrow ; n = wnoff + ni*16 + lgrp*4 + r
    const int wnoff = n0 + wn * (NF * 16);
    const int wmoff = m0 + wm * 128;
#pragma unroll
    for (int ni = 0; ni < NF; ++ni) {
        const int ncol = wnoff + ni * 16 + lgrp * 4;
        const float4 bv = *reinterpret_cast<const float4*>(&bias[ncol]);
#pragma unroll
        for (int mi = 0; mi < 8; ++mi) {
            const int row = wmoff + mi * 16 + lrow;
            float v0 = acc[mi][ni][0] + bv.x;
            float v1 = acc[mi][ni][1] + bv.y;
            float v2 = acc[mi][ni][2] + bv.z;
            float v3 = acc[mi][ni][3] + bv.w;
            if (RELU) {
                v0 = fmaxf(v0, 0.0f); v1 = fmaxf(v1, 0.0f);
                v2 = fmaxf(v2, 0.0f); v3 = fmaxf(v3, 0.0f);
            }
            const size_t base = (size_t)t * strideC + (size_t)row * N + ncol;
            if (OUTBF16) {
                uint2 p;
                p.x = (uint)f2bf(v0) | ((uint)f2bf(v1) << 16);
                p.y = (uint)f2bf(v2) | ((uint)f2bf(v3) << 16);
                *reinterpret_cast<uint2*>(&((ushort*)Cbase)[base]) = p;
            } else {
                float4 p = {v0, v1, v2, v3};
                *reinterpret_cast<float4*>(&((float*)Cbase)[base]) = p;
            }
        }
    }
}

extern "C" void kernel_launch(void* const* d_in, const int* in_sizes, int n_in,
                              void* d_out, int out_size, void* d_ws, size_t ws_size,
                              hipStream_t stream) {
    const float* x0 = (const float*)d_in[0];
    const float* x1 = (const float*)d_in[1];
    const float* x2 = (const float*)d_in[2];
    const float* x3 = (const float*)d_in[3];
    // d_in[4] = node_type (unused: nodes are blocked by type already)
    const float* W1 = (const float*)d_in[5];
    const float* b1 = (const float*)d_in[6];
    const float* W2[4] = {(const float*)d_in[7], (const float*)d_in[9],
                          (const float*)d_in[11], (const float*)d_in[13]};
    const float* b2[4] = {(const float*)d_in[8], (const float*)d_in[10],
                          (const float*)d_in[12], (const float*)d_in[14]};

    // workspace layout (bytes):
    //   H    bf16 [4][16384][1024]  134217728
    //   Xbf  bf16 [4][16384][512]    67108864
    //   W1T  bf16 [4][1024][512]      4194304
    //   W2T  bf16 [4][128][1024]      1048576
    //   b2p  f32  [4][128]                2048
    char* ws = (char*)d_ws;
    ushort* H   = (ushort*)ws;
    ushort* Xbf = (ushort*)(ws + 134217728ull);
    ushort* W1T = (ushort*)(ws + 134217728ull + 67108864ull);
    ushort* W2T = (ushort*)(ws + 134217728ull + 67108864ull + 4194304ull);
    float*  b2p = (float*)(ws + 134217728ull + 67108864ull + 4194304ull + 1048576ull);

    // conversions
    cvt_x_kernel<<<16384, 256, 0, stream>>>(x0, x1, x2, x3, Xbf);
    cvt_w_t_kernel<<<dim3(32, 16, 4), 256, 0, stream>>>(
        W1, W1T, DIN, DH, (size_t)DIN * DH, (size_t)DH * DIN);
    const int osz[4] = {128, 96, 64, 32};
    for (int t = 0; t < 4; ++t)
        cvt_w_t_kernel<<<dim3(4, 32, 1), 256, 0, stream>>>(
            W2[t], W2T + (size_t)t * MAXO * DH, DH, osz[t], 0, 0);
    pad_b2_kernel<<<1, 512, 0, stream>>>(b2[0], b2[1], b2[2], b2[3], b2p);

    // layer 1: H = relu(X @ W1 + b1), bf16 out
    // grid: 64 m-tiles x 4 n-tiles x 4 types = 1024 (n fastest for A reuse)
    gemm2p<256, true, true><<<1024, 512, 0, stream>>>(
        Xbf, W1T, b1, H,
        NNODE, DH, DIN, NNODE / 256,
        (size_t)NNODE * DIN, (size_t)DH * DIN, (size_t)DH, (size_t)NNODE * DH);

    // layer 2: out = H @ W2 + b2 (padded cols exactly 0), fp32 out
    // grid: 64 m-tiles x 1 n-tile x 4 types = 256
    gemm2p<128, false, false><<<256, 512, 0, stream>>>(
        H, W2T, b2p, d_out,
        NNODE, MAXO, DH, NNODE / 256,
        (size_t)NNODE * DH, (size_t)MAXO * DH, (size_t)MAXO, (size_t)NNODE * MAXO);
}

// Round 5
// 178.362 us; speedup vs baseline: 1.1647x; 1.0054x over previous
//
#include <hip/hip_runtime.h>
#include <hip/hip_bf16.h>

// ---------------------------------------------------------------------------
// QLayer: per-type 2-layer MLP.
//   h   = relu(x_t @ W1_t + b1_t)       [16384x512]@[512x1024]   (x4 types)
//   out = h @ W2_t + b2_t, padded to 128 cols                    (x4 types)
// Round 5: ONE barrier per K-tile. Double-buffered LDS + global_load_lds;
// per tile: {issue next-tile GLDs; (frag reads + MFMA) x2 kkk-halves;
// vmcnt(0); s_barrier}. No intra-tile barriers -> waves drift and LDS reads
// overlap MFMA across the 2 waves/SIMD. T1 XCD swizzle + T2 LDS swizzle kept.
// ---------------------------------------------------------------------------

typedef __attribute__((ext_vector_type(8))) short short8;
typedef __attribute__((ext_vector_type(4))) float f32x4;

#define NT 4
#define NNODE 16384
#define DIN 512
#define DH 1024
#define MAXO 128

static __device__ __forceinline__ ushort f2bf(float f) {
    __hip_bfloat16 h = __float2bfloat16(f);
    return *reinterpret_cast<ushort*>(&h);
}

#define GLD(gsrc, ldst)                                                        \
    __builtin_amdgcn_global_load_lds(                                          \
        (const __attribute__((address_space(1))) void*)(gsrc),                 \
        (__attribute__((address_space(3))) void*)(ldst), 16, 0, 0)

// --- x fp32 -> bf16, [4][16384][512] flat ---------------------------------
__global__ __launch_bounds__(256) void cvt_x_kernel(
    const float* __restrict__ x0, const float* __restrict__ x1,
    const float* __restrict__ x2, const float* __restrict__ x3,
    ushort* __restrict__ out) {
    const int i = blockIdx.x * 256 + threadIdx.x;     // 8-float chunk id
    const int per_t = (NNODE * DIN) / 8;              // 2^20 chunks per type
    const int t = i >> 20;
    const int loc = i & (per_t - 1);
    const float* x = (t == 0) ? x0 : (t == 1) ? x1 : (t == 2) ? x2 : x3;
    const float4* xv = reinterpret_cast<const float4*>(x) + (size_t)loc * 2;
    float4 a = xv[0], b = xv[1];
    union { short8 v; ushort u[8]; } r;
    float f[8] = {a.x, a.y, a.z, a.w, b.x, b.y, b.z, b.w};
#pragma unroll
    for (int j = 0; j < 8; ++j) r.u[j] = f2bf(f[j]);
    reinterpret_cast<short8*>(out)[i] = r.v;
}

// --- weight transpose+convert: in fp32 [R][Cin] -> out bf16 [Cout][R] ------
__global__ __launch_bounds__(256) void cvt_w_t_kernel(
    const float* __restrict__ in, ushort* __restrict__ out,
    int R, int Cin, size_t in_tstride, size_t out_tstride) {
    __shared__ float tile[32][33];
    const int t = blockIdx.z;
    in += (size_t)t * in_tstride;
    out += (size_t)t * out_tstride;
    const int c0 = blockIdx.x * 32, r0 = blockIdx.y * 32;
    const int cx = threadIdx.x & 31;
    const int ry = threadIdx.x >> 5;   // 0..7
#pragma unroll
    for (int j = 0; j < 4; ++j) {
        int rr = ry + j * 8;
        int c = c0 + cx;
        tile[rr][cx] = (c < Cin) ? in[(size_t)(r0 + rr) * Cin + c] : 0.0f;
    }
    __syncthreads();
#pragma unroll
    for (int j = 0; j < 4; ++j) {
        int cc = ry + j * 8;
        out[(size_t)(c0 + cc) * R + r0 + cx] = f2bf(tile[cx][cc]);
    }
}

// --- b2 pad to [4][128] fp32 ----------------------------------------------
__global__ void pad_b2_kernel(const float* __restrict__ b0, const float* __restrict__ b1,
                              const float* __restrict__ b2, const float* __restrict__ b3,
                              float* __restrict__ out) {
    const int i = threadIdx.x;            // 0..511
    const int t = i >> 7, n = i & 127;
    const int sz[4] = {128, 96, 64, 32};
    const float* b = (t == 0) ? b0 : (t == 1) ? b1 : (t == 2) ? b2 : b3;
    out[i] = (n < sz[t]) ? b[n] : 0.0f;
}

// ---------------------------------------------------------------------------
// 1-barrier-per-tile 256-tile bf16 GEMM: C = A[M][K] * BT[N][K]^T + bias
// BM=256, BN in {256,128}, BK=64, 512 threads = 8 waves (WM=2, WN=4).
// Wave tile 128 x (BN/4). LDS: dbuf x (A 32KB + B), XOR-swizzle both sides:
// byte(row,col16) = row*128 + ((col16*16) ^ ((row&7)<<4)).
//
// Per K-tile i:
//   issue GLDs for tile i+1 -> other buffer      (A 4 + B 4|2 per thread)
//   for kkk in {0,1}: { read frags (NF B + 8 A, b128); MFMA 8*NF }  (no bar)
//   s_waitcnt vmcnt(0)   // tile i+1 landed; loads are ~1 tile old -> cheap
//   s_barrier            // single publication point per tile
// MFMA operands swapped: D-row dim = n -> lane holds 4 consecutive n
// => vectorized epilogue (uint2 bf16 / float4 f32 stores).
// ---------------------------------------------------------------------------
template <int BN, bool RELU, bool OUTBF16>
__global__ __launch_bounds__(512, 1) void gemm1b(
    const ushort* __restrict__ Abase, const ushort* __restrict__ Bbase,
    const float* __restrict__ biasbase, void* __restrict__ Cbase,
    int N, int K, int MT,
    size_t strideA, size_t strideB, size_t strideBias, size_t strideC) {
    constexpr int NF = BN / 64;            // N-frags per wave (4 or 2)
    constexpr int NBC = BN * 8 / 512;      // B chunks per thread (4 or 2)
    constexpr int ABYTES = 256 * 64 * 2;   // 32 KB
    constexpr int BBYTES = BN * 64 * 2;    // 32 or 16 KB
    constexpr int BUF = ABYTES + BBYTES;
    __shared__ char lds[2 * BUF];

    // XCD-bijective block swizzle (grid % 8 == 0 by construction)
    const int cpx = gridDim.x >> 3;
    const int g = blockIdx.x;
    const int wg = (g & 7) * cpx + (g >> 3);
    const int NTL = N / BN;
    const int t = wg / (MT * NTL);
    const int rmn = wg % (MT * NTL);
    const int m0 = (rmn / NTL) * 256;
    const int n0 = (rmn % NTL) * BN;

    const ushort* A = Abase + (size_t)t * strideA;
    const ushort* Bp = Bbase + (size_t)t * strideB;
    const float* bias = biasbase + (size_t)t * strideBias;

    const int tid = threadIdx.x;
    const int lane = tid & 63;
    const int w = tid >> 6;
    const int wm = w >> 2, wn = w & 3;     // WM=2, WN=4
    const int lrow = lane & 15, lgrp = lane >> 4;

    // --- staging addresses (src col pre-swizzled, LDS dst linear) ----------
    const ushort* asrc[4];
    int adst[4];
#pragma unroll
    for (int j = 0; j < 4; ++j) {
        const int c = j * 512 + tid;           // chunk 0..2047
        const int r = c >> 3;                  // A row 0..255
        const int cb = ((c & 7) * 16) ^ ((r & 7) << 4);
        asrc[j] = A + (size_t)(m0 + r) * K + (cb >> 1);
        adst[j] = c * 16;
    }
    const ushort* bsrc[NBC];
    int bdst[NBC];
#pragma unroll
    for (int j = 0; j < NBC; ++j) {
        const int c = j * 512 + tid;           // chunk 0..BN*8-1
        const int r = c >> 3;                  // B row 0..BN-1
        const int cb = ((c & 7) * 16) ^ ((r & 7) << 4);
        bsrc[j] = Bp + (size_t)(n0 + r) * K + (cb >> 1);
        bdst[j] = ABYTES + c * 16;
    }

    f32x4 acc[8][NF] = {};
    const int NK = K / 64;

    // --- prologue: stage tile 0 into buf 0 ---------------------------------
#pragma unroll
    for (int j = 0; j < 4; ++j) GLD(asrc[j], lds + adst[j]);
#pragma unroll
    for (int j = 0; j < NBC; ++j) GLD(bsrc[j], lds + bdst[j]);
    asm volatile("s_waitcnt vmcnt(0)" ::: "memory");
    __builtin_amdgcn_s_barrier();
    __builtin_amdgcn_sched_barrier(0);

    for (int i = 0; i < NK; ++i) {
        const char* cu_ = lds + (i & 1) * BUF;
        char* nx_ = lds + ((i + 1) & 1) * BUF;
        const int ktn = (i + 1) * 64;
        const bool st = (i + 1 < NK);

        if (st) {
#pragma unroll
            for (int j = 0; j < 4; ++j) GLD(asrc[j] + ktn, nx_ + adst[j]);
#pragma unroll
            for (int j = 0; j < NBC; ++j) GLD(bsrc[j] + ktn, nx_ + bdst[j]);
        }

#pragma unroll
        for (int kkk = 0; kkk < 2; ++kkk) {
            short8 bfr[NF], af[8];
#pragma unroll
            for (int ni = 0; ni < NF; ++ni) {
                const int br = wn * (NF * 16) + ni * 16 + lrow;
                const int kb = (kkk * 64 + lgrp * 16) ^ ((br & 7) << 4);
                bfr[ni] = *(const short8*)(cu_ + ABYTES + br * 128 + kb);
            }
#pragma unroll
            for (int ml = 0; ml < 8; ++ml) {
                const int ar = wm * 128 + ml * 16 + lrow;
                const int kb = (kkk * 64 + lgrp * 16) ^ ((ar & 7) << 4);
                af[ml] = *(const short8*)(cu_ + ar * 128 + kb);
            }
            __builtin_amdgcn_s_setprio(1);
#pragma unroll
            for (int ml = 0; ml < 8; ++ml)
#pragma unroll
                for (int ni = 0; ni < NF; ++ni)
                    acc[ml][ni] = __builtin_amdgcn_mfma_f32_16x16x32_bf16(
                        bfr[ni], af[ml], acc[ml][ni], 0, 0, 0);
            __builtin_amdgcn_s_setprio(0);
        }

        if (st) {
            // publication: tile i+1 fully landed (loads issued ~1 tile ago)
            asm volatile("s_waitcnt vmcnt(0)" ::: "memory");
            __builtin_amdgcn_s_barrier();
            __builtin_amdgcn_sched_barrier(0);
        }
    }

    // --- epilogue (swapped operands): lane holds 4 consecutive n at reg r --
    // m = wmoff + mi*16 + lrow ; n = wnoff + ni*16 + lgrp*4 + r
    const int wnoff = n0 + wn * (NF * 16);
    const int wmoff = m0 + wm * 128;
#pragma unroll
    for (int ni = 0; ni < NF; ++ni) {
        const int ncol = wnoff + ni * 16 + lgrp * 4;
        const float4 bv = *reinterpret_cast<const float4*>(&bias[ncol]);
#pragma unroll
        for (int mi = 0; mi < 8; ++mi) {
            const int row = wmoff + mi * 16 + lrow;
            float v0 = acc[mi][ni][0] + bv.x;
            float v1 = acc[mi][ni][1] + bv.y;
            float v2 = acc[mi][ni][2] + bv.z;
            float v3 = acc[mi][ni][3] + bv.w;
            if (RELU) {
                v0 = fmaxf(v0, 0.0f); v1 = fmaxf(v1, 0.0f);
                v2 = fmaxf(v2, 0.0f); v3 = fmaxf(v3, 0.0f);
            }
            const size_t base = (size_t)t * strideC + (size_t)row * N + ncol;
            if (OUTBF16) {
                uint2 p;
                p.x = (uint)f2bf(v0) | ((uint)f2bf(v1) << 16);
                p.y = (uint)f2bf(v2) | ((uint)f2bf(v3) << 16);
                *reinterpret_cast<uint2*>(&((ushort*)Cbase)[base]) = p;
            } else {
                float4 p = {v0, v1, v2, v3};
                *reinterpret_cast<float4*>(&((float*)Cbase)[base]) = p;
            }
        }
    }
}

extern "C" void kernel_launch(void* const* d_in, const int* in_sizes, int n_in,
                              void* d_out, int out_size, void* d_ws, size_t ws_size,
                              hipStream_t stream) {
    const float* x0 = (const float*)d_in[0];
    const float* x1 = (const float*)d_in[1];
    const float* x2 = (const float*)d_in[2];
    const float* x3 = (const float*)d_in[3];
    // d_in[4] = node_type (unused: nodes are blocked by type already)
    const float* W1 = (const float*)d_in[5];
    const float* b1 = (const float*)d_in[6];
    const float* W2[4] = {(const float*)d_in[7], (const float*)d_in[9],
                          (const float*)d_in[11], (const float*)d_in[13]};
    const float* b2[4] = {(const float*)d_in[8], (const float*)d_in[10],
                          (const float*)d_in[12], (const float*)d_in[14]};

    // workspace layout (bytes):
    //   H    bf16 [4][16384][1024]  134217728
    //   Xbf  bf16 [4][16384][512]    67108864
    //   W1T  bf16 [4][1024][512]      4194304
    //   W2T  bf16 [4][128][1024]      1048576
    //   b2p  f32  [4][128]                2048
    char* ws = (char*)d_ws;
    ushort* H   = (ushort*)ws;
    ushort* Xbf = (ushort*)(ws + 134217728ull);
    ushort* W1T = (ushort*)(ws + 134217728ull + 67108864ull);
    ushort* W2T = (ushort*)(ws + 134217728ull + 67108864ull + 4194304ull);
    float*  b2p = (float*)(ws + 134217728ull + 67108864ull + 4194304ull + 1048576ull);

    // conversions
    cvt_x_kernel<<<16384, 256, 0, stream>>>(x0, x1, x2, x3, Xbf);
    cvt_w_t_kernel<<<dim3(32, 16, 4), 256, 0, stream>>>(
        W1, W1T, DIN, DH, (size_t)DIN * DH, (size_t)DH * DIN);
    const int osz[4] = {128, 96, 64, 32};
    for (int t = 0; t < 4; ++t)
        cvt_w_t_kernel<<<dim3(4, 32, 1), 256, 0, stream>>>(
            W2[t], W2T + (size_t)t * MAXO * DH, DH, osz[t], 0, 0);
    pad_b2_kernel<<<1, 512, 0, stream>>>(b2[0], b2[1], b2[2], b2[3], b2p);

    // layer 1: H = relu(X @ W1 + b1), bf16 out
    // grid: 64 m-tiles x 4 n-tiles x 4 types = 1024
    gemm1b<256, true, true><<<1024, 512, 0, stream>>>(
        Xbf, W1T, b1, H,
        DH, DIN, NNODE / 256,
        (size_t)NNODE * DIN, (size_t)DH * DIN, (size_t)DH, (size_t)NNODE * DH);

    // layer 2: out = H @ W2 + b2 (padded cols exactly 0), fp32 out
    // grid: 64 m-tiles x 1 n-tile x 4 types = 256
    gemm1b<128, false, false><<<256, 512, 0, stream>>>(
        H, W2T, b2p, d_out,
        MAXO, DH, NNODE / 256,
        (size_t)NNODE * DH, (size_t)MAXO * DH, (size_t)MAXO, (size_t)NNODE * MAXO);
}